// Round 17
// baseline (859.879 us; speedup 1.0000x reference)
//
#include <hip/hip_runtime.h>

// ---------------- problem constants ----------------
#define ETOT  500000
#define EHALF 250000
#define NENT  50000
#define NSEG  (2 * NENT)   // segments: half*NENT + dst
#define DD    200
#define BB    1024
#define NF    96
#define FLAT  38400   // 96*400

// fc split-K config
#define FC_KS     20
#define FC_KSLICE 1920    // 38400/20
#define FC_NCHUNK 60      // 1920/32

// logits config
#define LE 64             // entities per block (LDS strip)

// ---------------- workspace layout (float32 offsets) ----------------
#define OFF_AGG      0LL          // 20,000,000  ([0,10M)=agg_in, [10M,20M)=agg_out->aeh/ael)
// zeroed region: [ZSTART, ZEND)
#define ZSTART       20000000LL
#define OFF_CNT      20000000LL   // 100,004 ints (NSEG+1 used; becomes row_start after scan)
#define OFF_ACC0     20100004LL   //          2  (bn0 sum, sumsq)
#define OFF_ACC1     20100006LL   //        192  (bn1 sum[96], sumsq[96])
#define ZEND         20100198LL
// non-zeroed:
#define OFF_CURSOR   20304998LL   //    100,000 ints
#define OFF_BSUM     20404998LL   //        128 ints
#define OFF_ELIST    20405126LL   //    500,000 ints (dead after k_agg; wt planes reuse it)
#define OFF_WT       20405128LL   //    120,000 f32 = 240,000 ushort (3 transposed w hi+lo), 16B-aligned
#define OFF_DINV     20905126LL   //     50,000
#define OFF_RMAT     20955126LL   //     80,000
#define OFF_CHEQ     21035126LL   //    409,600
#define OFF_BN1S     21444726LL   //        192  (scale[96], shift[96])
#define OFF_X2H      21649720LL   //    102,400 f32 (= 204,800 ushort), 16B-aligned
#define OFF_X2L      21752120LL   //    102,400 f32
// total ws need ~= 21,854,520 f32 = 87.4 MB

// ---------------- d_out scratch layout (f32 offsets; out_size = 51,200,000) ----
// OD_CONV region is time-shared: [k_allent..k_cheq] it holds all_ent f32 (10M);
// from k_conv on it holds conv_out (39.3M). Strictly stream-ordered, no overlap in time.
#define OD_CONV 0LL          // 39,321,600 (1024 x 38400 conv output, f32)
#define OD_FWH  39321600LL   //  3,840,000 f32 = 7,680,000 ushort (fc_w hi plane)
#define OD_FWL  43161600LL   //  3,840,000 f32 (fc_w lo plane)
#define OD_PART 47001600LL   //  4,096,000 f32 (FC_KS x 1024 x 200 partials) -> ends 51,097,600

typedef __attribute__((ext_vector_type(8))) short bf16x8;
typedef __attribute__((ext_vector_type(4))) float f32x4;

__device__ inline void bf16split(float v, ushort& h, ushort& l) {
    unsigned u = __float_as_uint(v);
    unsigned hu = u & 0xffff0000u;
    h = (ushort)(hu >> 16);
    float lf = v - __uint_as_float(hu);
    l = (ushort)(__float_as_uint(lf) >> 16);
}

__device__ inline void split8(const float* e, bf16x8& h8, bf16x8& l8) {
#pragma unroll
    for (int t = 0; t < 8; t++) {
        ushort h, l;
        bf16split(e[t], h, l);
        h8[t] = (short)h;
        l8[t] = (short)l;
    }
}

// ================= CSR build =================

__global__ void k_hist(const int* __restrict__ ei, int* __restrict__ cnt) {
    int e = blockIdx.x * 256 + threadIdx.x;
    if (e < ETOT) {
        int seg = (e < EHALF ? 0 : NENT) + ei[ETOT + e];
        atomicAdd(&cnt[seg], 1);
    }
}

__global__ void k_dinv(const int* __restrict__ cnt, float* __restrict__ dinv) {
    int i = blockIdx.x * 256 + threadIdx.x;
    if (i < NENT) {
        int d = cnt[i] + cnt[NENT + i];
        dinv[i] = d > 0 ? rsqrtf((float)d) : 0.f;
    }
}

__global__ void k_scan1(int* __restrict__ cnt, int* __restrict__ bsum) {
    __shared__ int S[256];
    int base = blockIdx.x * 1024 + threadIdx.x * 4;
    int v[4], s = 0;
#pragma unroll
    for (int i = 0; i < 4; i++) { v[i] = (base + i <= NSEG) ? cnt[base + i] : 0; s += v[i]; }
    S[threadIdx.x] = s;
    __syncthreads();
    for (int off = 1; off < 256; off <<= 1) {
        int t = (threadIdx.x >= off) ? S[threadIdx.x - off] : 0;
        __syncthreads();
        S[threadIdx.x] += t;
        __syncthreads();
    }
    int run = S[threadIdx.x] - s;
#pragma unroll
    for (int i = 0; i < 4; i++) {
        if (base + i <= NSEG) cnt[base + i] = run;
        run += v[i];
    }
    if (threadIdx.x == 255) bsum[blockIdx.x] = S[255];
}

__global__ void k_scan2(int* __restrict__ bsum) {
    __shared__ int S[128];
    int v = (threadIdx.x < 98) ? bsum[threadIdx.x] : 0;
    S[threadIdx.x] = v;
    __syncthreads();
    for (int off = 1; off < 128; off <<= 1) {
        int t = (threadIdx.x >= off) ? S[threadIdx.x - off] : 0;
        __syncthreads();
        S[threadIdx.x] += t;
        __syncthreads();
    }
    if (threadIdx.x < 98) bsum[threadIdx.x] = S[threadIdx.x] - v;
}

__global__ void k_scan3(int* __restrict__ cnt, const int* __restrict__ bsum,
                        int* __restrict__ cursor) {
    int add = bsum[blockIdx.x];
    int base = blockIdx.x * 1024 + threadIdx.x * 4;
#pragma unroll
    for (int i = 0; i < 4; i++) {
        int idx = base + i;
        if (idx <= NSEG) {
            int v = cnt[idx] + add;
            cnt[idx] = v;
            if (idx < NSEG) cursor[idx] = v;
        }
    }
}

__global__ void k_fill(const int* __restrict__ ei, int* __restrict__ cursor,
                       int* __restrict__ elist) {
    int e = blockIdx.x * 256 + threadIdx.x;
    if (e < ETOT) {
        int seg = (e < EHALF ? 0 : NENT) + ei[ETOT + e];
        int pos = atomicAdd(&cursor[seg], 1);
        elist[pos] = e;
    }
}

// gather-aggregate: one wave per segment (4 waves/block), no float atomics.
// Index loads (elist/ei/et) software-pipelined one edge ahead so the dependent
// chain elist->ei/et->emb/rel overlaps across edges.
__global__ void k_agg(const int* __restrict__ ei, const int* __restrict__ et,
                      const int* __restrict__ row_start, const int* __restrict__ elist,
                      const float* __restrict__ emb, const float* __restrict__ rel,
                      const float* __restrict__ dinv, float* __restrict__ agg) {
    int seg = blockIdx.x * 4 + (threadIdx.x >> 6);
    int lane = threadIdx.x & 63;
    int dst = seg - (seg >= NENT ? NENT : 0);
    float dd = dinv[dst];
    int s = row_start[seg], e = row_start[seg + 1];
    bool act = lane < 50;
    float4 acc = {0.f, 0.f, 0.f, 0.f};
    if (s < e) {
        int ed = elist[s];
        int src = ei[ed];
        int t = et[ed];
        for (int i = s; i < e; i++) {
            int src_c = src, t_c = t;
            if (i + 1 < e) {          // prefetch next edge's indices
                int ed2 = elist[i + 1];
                src = ei[ed2];
                t = et[ed2];
            }
            float nrm = dinv[src_c] * dd;
            if (act) {
                float4 a = *(const float4*)&emb[(long long)src_c * DD + lane * 4];
                float4 b = *(const float4*)&rel[t_c * DD + lane * 4];
                acc.x += (a.x - b.x) * nrm;
                acc.y += (a.y - b.y) * nrm;
                acc.z += (a.z - b.z) * nrm;
                acc.w += (a.w - b.w) * nrm;
            }
        }
    }
    if (act) *(float4*)&agg[(long long)seg * DD + lane * 4] = acc;
}

// ================= encoder GEMMs =================

// transpose + hi/lo-split the three 200x200 weights: wt[s][j][k] = split(w_s[k][j])
__global__ void k_cvt3w(const float* __restrict__ w_in, const float* __restrict__ w_out,
                        const float* __restrict__ w_loop,
                        ushort* __restrict__ wth, ushort* __restrict__ wtl) {
    int idx = blockIdx.x * 256 + threadIdx.x;
    if (idx >= 3 * DD * DD) return;
    int s = idx / (DD * DD);
    int rem = idx - s * DD * DD;
    int j = rem / DD, k = rem - (rem / DD) * DD;
    const float* w = (s == 0) ? w_in : (s == 1) ? w_out : w_loop;
    ushort h, l;
    bf16split(w[k * DD + j], h, l);
    wth[idx] = h;
    wtl[idx] = l;
}

// all_ent = tanh((agg_in@w_in + agg_out@w_out + (emb-loop_rel)@w_loop)/3) via bf16-split MFMA.
__global__ __launch_bounds__(256) void k_allent_mfma(
        const float* __restrict__ agg, const float* __restrict__ emb,
        const float* __restrict__ loop_rel,
        const ushort* __restrict__ wth, const ushort* __restrict__ wtl,
        float* __restrict__ all_ent) {
    __shared__ __align__(16) ushort Bh[2][112][36];   // stride 36 -> 2-way banks (free)
    __shared__ __align__(16) ushort Bl[2][112][36];
    __shared__ float lr[DD];
    int tid = threadIdx.x;
    for (int i = tid; i < DD; i += 256) lr[i] = loop_rel[i];
    int wid = tid >> 6, lane = tid & 63, l15 = lane & 15, q = lane >> 4;
    int r0 = blockIdx.x * 64;
    int nh = blockIdx.y;
    int row = r0 + wid * 16 + l15;
    if (row > NENT - 1) row = NENT - 1;
    const float* apa = &agg[(long long)row * DD];
    const float* apb = &agg[(long long)(NENT + row) * DD];
    const float* apc = &emb[(long long)row * DD];

    bool stg = tid < 224;
    int srow = tid - (tid >= 112 ? 112 : 0);
    if (srow > 111) srow = 0;
    bool spl = (tid >= 112) && stg;
    int sj = nh * 112 + srow;
    int sjr = sj < DD ? sj : DD - 1;
    const ushort* bplane = spl ? wtl : wth;
    int srowoff = sjr * DD;
    ushort* d0 = spl ? &Bl[0][srow][0] : &Bh[0][srow][0];
    ushort* d1 = spl ? &Bl[1][srow][0] : &Bh[1][srow][0];

    f32x4 zero4 = {0.f, 0.f, 0.f, 0.f};
    f32x4 acc[7];
#pragma unroll
    for (int n = 0; n < 7; n++) acc[n] = zero4;

    uint4 w0 = {0u,0u,0u,0u}, w1 = {0u,0u,0u,0u}, w2 = {0u,0u,0u,0u}, w3 = {0u,0u,0u,0u};
    if (stg) {
        const ushort* src = bplane + srowoff;
        w0 = *(const uint4*)&src[0];
        w1 = *(const uint4*)&src[8];
        w2 = *(const uint4*)&src[16];
        w3 = *(const uint4*)&src[24];
        *(uint4*)&d0[0]  = w0;
        *(uint4*)&d0[8]  = w1;
        *(uint4*)&d0[16] = w2;
        *(uint4*)&d0[24] = w3;
    }
    float4 a1, a2;
    {
        int k0 = q * 8;
        a1 = *(const float4*)&apa[k0];
        a2 = *(const float4*)&apa[k0 + 4];
    }
    __syncthreads();

    for (int t = 0; t < 21; t++) {
        int buf = t & 1;
        int s = t / 7, kk = t - s * 7;
        bool prt = (kk == 6);
        int k0 = prt ? 192 : kk * 32 + q * 8;
        bool act = !prt || (q == 0);
        bool more = (t + 1 < 21);
        if (stg && more) {
            int t2 = t + 1, ss = t2 / 7, k2 = t2 - ss * 7;
            bool p2 = (k2 == 6);
            int koff2 = p2 ? 192 : k2 * 32;
            const ushort* src = bplane + ss * (DD * DD) + srowoff + koff2;
            uint4 zz = {0u,0u,0u,0u};
            w0 = *(const uint4*)&src[0];
            w1 = p2 ? zz : *(const uint4*)&src[8];
            w2 = p2 ? zz : *(const uint4*)&src[16];
            w3 = p2 ? zz : *(const uint4*)&src[24];
        }
        float4 n1 = {0.f, 0.f, 0.f, 0.f}, n2 = {0.f, 0.f, 0.f, 0.f};
        if (more) {
            int t2 = t + 1, ss = t2 / 7, k2 = t2 - ss * 7;
            bool p2 = (k2 == 6);
            int ka = p2 ? 192 : k2 * 32 + q * 8;
            const float* apn = (ss == 0) ? apa : (ss == 1) ? apb : apc;
            if (!p2 || q == 0) {
                n1 = *(const float4*)&apn[ka];
                n2 = *(const float4*)&apn[ka + 4];
            }
        }
        float e[8] = {0.f, 0.f, 0.f, 0.f, 0.f, 0.f, 0.f, 0.f};
        if (act) {
            float4 v1 = a1, v2 = a2;
            if (s == 2) {
                float4 u1 = *(const float4*)&lr[k0];
                float4 u2 = *(const float4*)&lr[k0 + 4];
                v1.x -= u1.x; v1.y -= u1.y; v1.z -= u1.z; v1.w -= u1.w;
                v2.x -= u2.x; v2.y -= u2.y; v2.z -= u2.z; v2.w -= u2.w;
            }
            e[0] = v1.x; e[1] = v1.y; e[2] = v1.z; e[3] = v1.w;
            e[4] = v2.x; e[5] = v2.y; e[6] = v2.z; e[7] = v2.w;
        }
        bf16x8 ah, al;
        split8(e, ah, al);
#pragma unroll
        for (int n = 0; n < 7; n++) {
            bf16x8 bh = *(const bf16x8*)&Bh[buf][n * 16 + l15][q * 8];
            bf16x8 bl = *(const bf16x8*)&Bl[buf][n * 16 + l15][q * 8];
            acc[n] = __builtin_amdgcn_mfma_f32_16x16x32_bf16(ah, bh, acc[n], 0, 0, 0);
            acc[n] = __builtin_amdgcn_mfma_f32_16x16x32_bf16(ah, bl, acc[n], 0, 0, 0);
            acc[n] = __builtin_amdgcn_mfma_f32_16x16x32_bf16(al, bh, acc[n], 0, 0, 0);
        }
        if (stg && more) {
            ushort* d = buf ? d0 : d1;
            *(uint4*)&d[0]  = w0;
            *(uint4*)&d[8]  = w1;
            *(uint4*)&d[16] = w2;
            *(uint4*)&d[24] = w3;
        }
        __syncthreads();
        a1 = n1; a2 = n2;
    }
#pragma unroll
    for (int n = 0; n < 7; n++) {
        int j = nh * 112 + n * 16 + l15;
        if (j < DD) {
            int rowb = r0 + wid * 16 + q * 4;
#pragma unroll
            for (int r = 0; r < 4; r++) {
                if (rowb + r < NENT)
                    all_ent[(long long)(rowb + r) * DD + j] = tanhf(acc[n][r] * (1.f / 3.f));
            }
        }
    }
}

// convert all_ent f32 -> bf16 hi/lo (over agg_out region), 4 elems/thread
__global__ void k_cvt(const float* __restrict__ src, ushort* __restrict__ hi,
                      ushort* __restrict__ lo) {
    long long i = (long long)(blockIdx.x * 256 + threadIdx.x) * 4;
    if (i >= (long long)NENT * DD) return;
    float4 v = *(const float4*)&src[i];
    ushort4 h, l;
    bf16split(v.x, h.x, l.x);
    bf16split(v.y, h.y, l.y);
    bf16split(v.z, h.z, l.z);
    bf16split(v.w, h.w, l.w);
    *(ushort4*)&hi[i] = h;
    *(ushort4*)&lo[i] = l;
}

// convert fc_w f32 -> bf16 hi/lo planes (into d_out tail)
__global__ void k_cvtw(const float* __restrict__ src, ushort* __restrict__ hi,
                       ushort* __restrict__ lo) {
    long long i = (long long)(blockIdx.x * 256 + threadIdx.x) * 4;
    if (i >= (long long)DD * FLAT) return;
    float4 v = *(const float4*)&src[i];
    ushort4 h, l;
    bf16split(v.x, h.x, l.x);
    bf16split(v.y, h.y, l.y);
    bf16split(v.z, h.z, l.z);
    bf16split(v.w, h.w, l.w);
    *(ushort4*)&hi[i] = h;
    *(ushort4*)&lo[i] = l;
}

__global__ void k_rmat(const float* __restrict__ init_rel, const float* __restrict__ w_rel,
                       float* __restrict__ rmat) {
    __shared__ float S[16][DD];
    int r0 = blockIdx.x * 16;
    for (int i = threadIdx.x; i < 16 * DD; i += 256)
        S[i / DD][i % DD] = init_rel[(r0 + i / DD) * DD + i % DD];
    __syncthreads();
    int j = threadIdx.x;
    if (j < DD) {
        float acc[16];
#pragma unroll
        for (int rr = 0; rr < 16; rr++) acc[rr] = 0.f;
        for (int k = 0; k < DD; k += 4) {
            float wx = w_rel[(k + 0) * DD + j], wy = w_rel[(k + 1) * DD + j],
                  wz = w_rel[(k + 2) * DD + j], ww = w_rel[(k + 3) * DD + j];
#pragma unroll
            for (int rr = 0; rr < 16; rr++) {
                float4 a = *(const float4*)&S[rr][k];
                acc[rr] += a.x * wx + a.y * wy + a.z * wz + a.w * ww;
            }
        }
#pragma unroll
        for (int rr = 0; rr < 16; rr++) rmat[(r0 + rr) * DD + j] = acc[rr];
    }
}

// ================= decoder =================

__global__ void k_cheq(const int* __restrict__ sub, const int* __restrict__ rel,
                       const int* __restrict__ perm, const float* __restrict__ all_ent,
                       const float* __restrict__ rmat, float* __restrict__ cheq,
                       float* __restrict__ acc0) {
    int i = blockIdx.x * 256 + threadIdx.x;
    int b = i / 400, p = i % 400;
    int c = perm[p];
    float v = (c < DD) ? all_ent[(long long)sub[b] * DD + c]
                       : rmat[rel[b] * DD + (c - DD)];
    cheq[i] = v;
    __shared__ float s1[256], s2[256];
    s1[threadIdx.x] = v;
    s2[threadIdx.x] = v * v;
    __syncthreads();
    for (int st = 128; st > 0; st >>= 1) {
        if (threadIdx.x < st) { s1[threadIdx.x] += s1[threadIdx.x + st]; s2[threadIdx.x] += s2[threadIdx.x + st]; }
        __syncthreads();
    }
    if (threadIdx.x == 0) { atomicAdd(&acc0[0], s1[0]); atomicAdd(&acc0[1], s2[0]); }
}

// bn0-normalize + circular pad + 9x9 conv + bn1 stats (register sliding window).
__global__ void k_conv(const float* __restrict__ cheq, const float* __restrict__ acc0,
                       const float* __restrict__ bn0_g, const float* __restrict__ bn0_b,
                       const float* __restrict__ filt, float* __restrict__ conv_out,
                       float* __restrict__ acc1) {
    __shared__ __align__(16) float xp[28][36];   // 4 KB
    __shared__ float fl[NF * 81];                // 31.1 KB
    __shared__ float csum[NF], csq[NF];
    int b = blockIdx.x;
    const float invN = 1.f / (BB * 400.f);
    float mean = acc0[0] * invN;
    float var = acc0[1] * invN - mean * mean;
    float sc = rsqrtf(var + 1e-5f) * bn0_g[0];
    float sh = bn0_b[0] - mean * sc;
    for (int i = threadIdx.x; i < 28 * 28; i += 256) {
        int r = i / 28, c = i % 28;
        int rr = (r + 16) % 20, cc = (c + 16) % 20;
        xp[r][c] = cheq[b * 400 + rr * 20 + cc] * sc + sh;
    }
    for (int i = threadIdx.x; i < NF * 81; i += 256) fl[i] = filt[i];
    if (threadIdx.x < NF) { csum[threadIdx.x] = 0.f; csq[threadIdx.x] = 0.f; }
    __syncthreads();
    for (int t = threadIdx.x; t < NF * 20; t += 256) {
        int ch = t / 20, row = t % 20;
        float acc[20];
#pragma unroll
        for (int c2 = 0; c2 < 20; c2++) acc[c2] = 0.f;
        for (int di = 0; di < 9; di++) {
            float xr[28];
#pragma unroll
            for (int g = 0; g < 7; g++) {
                float4 v = *(const float4*)&xp[row + di][g * 4];
                xr[g * 4 + 0] = v.x; xr[g * 4 + 1] = v.y;
                xr[g * 4 + 2] = v.z; xr[g * 4 + 3] = v.w;
            }
            float f[9];
#pragma unroll
            for (int dj = 0; dj < 9; dj++) f[dj] = fl[ch * 81 + di * 9 + dj];
#pragma unroll
            for (int dj = 0; dj < 9; dj++)
#pragma unroll
                for (int c2 = 0; c2 < 20; c2++)
                    acc[c2] = fmaf(xr[c2 + dj], f[dj], acc[c2]);
        }
        float s = 0.f, q = 0.f;
        long long base = (long long)b * FLAT + ch * 400 + row * 20;
#pragma unroll
        for (int c2 = 0; c2 < 20; c2++) {
            float v = acc[c2];
            s += v; q += v * v;
            conv_out[base + c2] = v;
        }
        atomicAdd(&csum[ch], s);
        atomicAdd(&csq[ch], q);
    }
    __syncthreads();
    if (threadIdx.x < NF) {
        atomicAdd(&acc1[threadIdx.x], csum[threadIdx.x]);
        atomicAdd(&acc1[NF + threadIdx.x], csq[threadIdx.x]);
    }
}

__global__ void k_bn1fin(const float* __restrict__ acc1, const float* __restrict__ g1,
                         const float* __restrict__ b1, float* __restrict__ bn1s) {
    int c = threadIdx.x;
    if (c >= NF) return;
    const float invN = 1.f / (BB * 400.f);
    float m = acc1[c] * invN;
    float v = acc1[NF + c] * invN - m * m;
    float sc = rsqrtf(v + 1e-5f) * g1[c];
    bn1s[c] = sc;
    bn1s[NF + c] = b1[c] - m * sc;
}

// ---- fc GEMM via bf16-split MFMA: merged N-halves (A read ONCE), LDS-staged B ----
// grid (16 M, 20 K); 512 thr = 8 waves: wm = wid>>1 (M-sub 0..3), wnh = wid&1 (N-half).
// Wave tile 16 rows x 112 cols. Both wnh waves of a wm read identical A rows -> L1 hit,
// halving conv_out HBM traffic vs the old (16,2,20) grid. B LDS [2][224][36] (~65 KB,
// 2 blocks/CU = 16 waves/CU). Spill-free named-register staging; one barrier per chunk.
__global__ __launch_bounds__(512) void k_fc_mfma(
        const float* __restrict__ conv_out, const float* __restrict__ bn1s,
        const ushort* __restrict__ fwh, const ushort* __restrict__ fwl,
        float* __restrict__ part) {
    __shared__ __align__(16) ushort Bh[2][224][36];
    __shared__ __align__(16) ushort Bl[2][224][36];
    __shared__ float bns[192];
    int tid = threadIdx.x;
    for (int i = tid; i < 192; i += 512) bns[i] = bn1s[i];
    int wid = tid >> 6, lane = tid & 63, l15 = lane & 15, q = lane >> 4;
    int wm = wid >> 1;          // 0..3
    int wnh = wid & 1;          // 0..1
    int b0 = blockIdx.x * 64;
    int ksl = blockIdx.y;
    int kbase = ksl * FC_KSLICE;

    const float* ap = conv_out + (long long)(b0 + wm * 16 + l15) * FLAT;

    // stager: threads 0..447 own (plane = t>=224, row = t%224); row maps to j (clamp 199)
    bool stg = tid < 448;
    bool spl = (tid >= 224) && stg;
    int srow = spl ? tid - 224 : tid;
    if (srow > 223) srow = 0;
    int sjr = srow < DD ? srow : DD - 1;
    const ushort* bsrc = (spl ? fwl : fwh) + (long long)sjr * FLAT + kbase;
    ushort* d0 = spl ? &Bl[0][srow][0] : &Bh[0][srow][0];
    ushort* d1 = spl ? &Bl[1][srow][0] : &Bh[1][srow][0];

    f32x4 zero4 = {0.f, 0.f, 0.f, 0.f};
    f32x4 acc[7];
#pragma unroll
    for (int n = 0; n < 7; n++) acc[n] = zero4;

    uint4 s0 = {0u,0u,0u,0u}, s1 = {0u,0u,0u,0u}, s2 = {0u,0u,0u,0u}, s3 = {0u,0u,0u,0u};
    if (stg) {
        s0 = *(const uint4*)&bsrc[0];
        s1 = *(const uint4*)&bsrc[8];
        s2 = *(const uint4*)&bsrc[16];
        s3 = *(const uint4*)&bsrc[24];
        *(uint4*)&d0[0]  = s0;
        *(uint4*)&d0[8]  = s1;
        *(uint4*)&d0[16] = s2;
        *(uint4*)&d0[24] = s3;
    }
    float4 a1, a2;
    {
        int k0 = kbase + q * 8;
        a1 = *(const float4*)&ap[k0];
        a2 = *(const float4*)&ap[k0 + 4];
    }
    __syncthreads();

    for (int c = 0; c < FC_NCHUNK; c++) {
        int buf = c & 1;
        int kc = kbase + c * 32 + q * 8;
        bool more = (c + 1 < FC_NCHUNK);
        if (stg && more) {
            int kn = (c + 1) * 32;
            s0 = *(const uint4*)&bsrc[kn];
            s1 = *(const uint4*)&bsrc[kn + 8];
            s2 = *(const uint4*)&bsrc[kn + 16];
            s3 = *(const uint4*)&bsrc[kn + 24];
        }
        float4 n1 = {0.f, 0.f, 0.f, 0.f}, n2 = {0.f, 0.f, 0.f, 0.f};
        if (more) {
            n1 = *(const float4*)&ap[kc + 32];
            n2 = *(const float4*)&ap[kc + 36];
        }
        int ch = kc / 400;
        float sc = bns[ch], sh = bns[96 + ch];
        float e[8] = {
            fmaxf(a1.x * sc + sh, 0.f), fmaxf(a1.y * sc + sh, 0.f),
            fmaxf(a1.z * sc + sh, 0.f), fmaxf(a1.w * sc + sh, 0.f),
            fmaxf(a2.x * sc + sh, 0.f), fmaxf(a2.y * sc + sh, 0.f),
            fmaxf(a2.z * sc + sh, 0.f), fmaxf(a2.w * sc + sh, 0.f)};
        bf16x8 ah, al;
        split8(e, ah, al);
#pragma unroll
        for (int n = 0; n < 7; n++) {
            int brow = wnh * 112 + n * 16 + l15;
            bf16x8 bh = *(const bf16x8*)&Bh[buf][brow][q * 8];
            bf16x8 bl = *(const bf16x8*)&Bl[buf][brow][q * 8];
            acc[n] = __builtin_amdgcn_mfma_f32_16x16x32_bf16(ah, bh, acc[n], 0, 0, 0);
            acc[n] = __builtin_amdgcn_mfma_f32_16x16x32_bf16(ah, bl, acc[n], 0, 0, 0);
            acc[n] = __builtin_amdgcn_mfma_f32_16x16x32_bf16(al, bh, acc[n], 0, 0, 0);
        }
        if (stg && more) {
            ushort* d = buf ? d0 : d1;
            *(uint4*)&d[0]  = s0;
            *(uint4*)&d[8]  = s1;
            *(uint4*)&d[16] = s2;
            *(uint4*)&d[24] = s3;
        }
        __syncthreads();
        a1 = n1; a2 = n2;
    }
    // epilogue: part[ksl][row][j]; C layout row=q*4+r, col=l15 per 16x16 frag
    long long pbase = (long long)ksl * (BB * DD);
#pragma unroll
    for (int n = 0; n < 7; n++) {
        int j = wnh * 112 + n * 16 + l15;
        if (j < DD) {
            int rowb = b0 + wm * 16 + q * 4;
#pragma unroll
            for (int r = 0; r < 4; r++)
                part[pbase + (long long)(rowb + r) * DD + j] = acc[n][r];
        }
    }
}

// bn2 over batch, folding the split-K reduction; emits x2 bf16 hi/lo only
__global__ void k_bn2(const float* __restrict__ part, const float* __restrict__ fc_b,
                      const float* __restrict__ g2, const float* __restrict__ b2,
                      ushort* __restrict__ x2h, ushort* __restrict__ x2l) {
    int j = blockIdx.x;
    float vals[4];
    float s = 0.f, q = 0.f;
#pragma unroll
    for (int i = 0; i < 4; i++) {
        int b = threadIdx.x + i * 256;
        float v = fc_b[j];
#pragma unroll
        for (int ks = 0; ks < FC_KS; ks++)
            v += part[(long long)ks * (BB * DD) + (long long)b * DD + j];
        vals[i] = v;
        s += v; q += v * v;
    }
    __shared__ float r1[256], r2[256];
    __shared__ float bc[2];
    r1[threadIdx.x] = s; r2[threadIdx.x] = q;
    __syncthreads();
    for (int st = 128; st > 0; st >>= 1) {
        if (threadIdx.x < st) { r1[threadIdx.x] += r1[threadIdx.x + st]; r2[threadIdx.x] += r2[threadIdx.x + st]; }
        __syncthreads();
    }
    if (threadIdx.x == 0) {
        float m = r1[0] * (1.f / BB);
        float v = r2[0] * (1.f / BB) - m * m;
        float sc = rsqrtf(v + 1e-5f) * g2[j];
        bc[0] = sc; bc[1] = b2[j] - m * sc;
    }
    __syncthreads();
    float sc = bc[0], sh = bc[1];
#pragma unroll
    for (int i = 0; i < 4; i++) {
        int b = threadIdx.x + i * 256;
        float v = fmaxf(vals[i] * sc + sh, 0.f);
        ushort h, l;
        bf16split(v, h, l);
        x2h[b * DD + j] = h;
        x2l[b * DD + j] = l;
    }
}

// logits = sigmoid(x2 @ all_ent^T + bias) via bf16-split MFMA, B-strip-resident.
// (latency-floor kernel — unchanged from round 16)
__global__ __launch_bounds__(512) void k_logits_mfma(
        const ushort* __restrict__ x2h, const ushort* __restrict__ x2l,
        const ushort* __restrict__ aeh, const ushort* __restrict__ ael,
        const float* __restrict__ bias, float* __restrict__ out) {
    __shared__ ushort Bhs[LE * DD];            // 25.6 KB
    __shared__ ushort Bls[LE * DD];            // 25.6 KB
    __shared__ __align__(16) float Tw[8][16][36];   // 18.4 KB per-wave transpose tiles
    int e0 = blockIdx.x * LE;
    for (int i = threadIdx.x; i < 2 * LE * 25; i += 512) {   // 3200 uint4
        int pl = i >= LE * 25;
        int ii = pl ? i - LE * 25 : i;
        int row = ii / 25, seg = ii % 25;
        int e = e0 + row;
        if (e > NENT - 1) e = NENT - 1;
        const ushort* src = (pl ? ael : aeh) + (long long)e * DD + seg * 8;
        uint4 v = *(const uint4*)src;
        if (pl) *(uint4*)&Bls[row * DD + seg * 8] = v;
        else    *(uint4*)&Bhs[row * DD + seg * 8] = v;
    }
    __syncthreads();

    int wid = threadIdx.x >> 6;
    int lane = threadIdx.x & 63;
    int l15 = lane & 15, q = lane >> 4;
    int wm = wid >> 1;
    int wn = wid & 1;

    int nbase0 = (wn * 32 + l15) * DD;
    int nbase1 = (wn * 32 + 16 + l15) * DD;

    int tr = lane >> 3;            // 0..7 (+8 for second read)
    int tc = (lane & 7) * 4;       // 0..28
    int ceg = e0 + wn * 32 + tc;   // global entity col (4-aligned; NENT%4==0)
    bool cval = ceg < NENT;
    float4 bb = {0.f, 0.f, 0.f, 0.f};
    if (cval) bb = *(const float4*)&bias[ceg];

    f32x4 zero4 = {0.f, 0.f, 0.f, 0.f};
    bf16x8 zf = {0, 0, 0, 0, 0, 0, 0, 0};
    const int STEP = 128 * DD;

    const ushort* ah0 = x2h + (long long)(wm * 32 + l15) * DD;
    const ushort* al0 = x2l + (long long)(wm * 32 + l15) * DD;
    const ushort* ah1 = ah0 + 16 * DD;
    const ushort* al1 = al0 + 16 * DD;

    bf16x8 pa_h0, pa_l0, pa_h1, pa_l1;
    {
        int k0 = q * 8;
        pa_h0 = *(const bf16x8*)&ah0[k0];
        pa_l0 = *(const bf16x8*)&al0[k0];
        pa_h1 = *(const bf16x8*)&ah1[k0];
        pa_l1 = *(const bf16x8*)&al1[k0];
    }

    for (int it = 0; it < 8; it++) {
        f32x4 acc00 = zero4, acc01 = zero4, acc10 = zero4, acc11 = zero4;
#pragma unroll
        for (int kk = 0; kk < 6; kk++) {
            int kn = (kk < 5) ? (kk + 1) * 32 + q * 8 : 192;
            bf16x8 na_h0 = *(const bf16x8*)&ah0[kn];
            bf16x8 na_l0 = *(const bf16x8*)&al0[kn];
            bf16x8 na_h1 = *(const bf16x8*)&ah1[kn];
            bf16x8 na_l1 = *(const bf16x8*)&al1[kn];
            int kb = kk * 32 + q * 8;
            bf16x8 bh0 = *(const bf16x8*)&Bhs[nbase0 + kb];
            bf16x8 bl0 = *(const bf16x8*)&Bls[nbase0 + kb];
            bf16x8 bh1 = *(const bf16x8*)&Bhs[nbase1 + kb];
            bf16x8 bl1 = *(const bf16x8*)&Bls[nbase1 + kb];
            acc00 = __builtin_amdgcn_mfma_f32_16x16x32_bf16(pa_h0, bh0, acc00, 0, 0, 0);
            acc00 = __builtin_amdgcn_mfma_f32_16x16x32_bf16(pa_h0, bl0, acc00, 0, 0, 0);
            acc00 = __builtin_amdgcn_mfma_f32_16x16x32_bf16(pa_l0, bh0, acc00, 0, 0, 0);
            acc01 = __builtin_amdgcn_mfma_f32_16x16x32_bf16(pa_h0, bh1, acc01, 0, 0, 0);
            acc01 = __builtin_amdgcn_mfma_f32_16x16x32_bf16(pa_h0, bl1, acc01, 0, 0, 0);
            acc01 = __builtin_amdgcn_mfma_f32_16x16x32_bf16(pa_l0, bh1, acc01, 0, 0, 0);
            acc10 = __builtin_amdgcn_mfma_f32_16x16x32_bf16(pa_h1, bh0, acc10, 0, 0, 0);
            acc10 = __builtin_amdgcn_mfma_f32_16x16x32_bf16(pa_h1, bl0, acc10, 0, 0, 0);
            acc10 = __builtin_amdgcn_mfma_f32_16x16x32_bf16(pa_l1, bh0, acc10, 0, 0, 0);
            acc11 = __builtin_amdgcn_mfma_f32_16x16x32_bf16(pa_h1, bh1, acc11, 0, 0, 0);
            acc11 = __builtin_amdgcn_mfma_f32_16x16x32_bf16(pa_h1, bl1, acc11, 0, 0, 0);
            acc11 = __builtin_amdgcn_mfma_f32_16x16x32_bf16(pa_l1, bh1, acc11, 0, 0, 0);
            pa_h0 = na_h0; pa_l0 = na_l0; pa_h1 = na_h1; pa_l1 = na_l1;
        }
        {
            bf16x8 na_h0 = zf, na_l0 = zf, na_h1 = zf, na_l1 = zf;
            if (it + 1 < 8) {
                int k0 = q * 8;
                na_h0 = *(const bf16x8*)&ah0[STEP + k0];
                na_l0 = *(const bf16x8*)&al0[STEP + k0];
                na_h1 = *(const bf16x8*)&ah1[STEP + k0];
                na_l1 = *(const bf16x8*)&al1[STEP + k0];
            }
            bool a0 = (q == 0);
            bf16x8 xh0 = a0 ? pa_h0 : zf, xl0 = a0 ? pa_l0 : zf;
            bf16x8 xh1 = a0 ? pa_h1 : zf, xl1 = a0 ? pa_l1 : zf;
            bf16x8 bh0 = a0 ? *(const bf16x8*)&Bhs[nbase0 + 192] : zf;
            bf16x8 bl0 = a0 ? *(const bf16x8*)&Bls[nbase0 + 192] : zf;
            bf16x8 bh1 = a0 ? *(const bf16x8*)&Bhs[nbase1 + 192] : zf;
            bf16x8 bl1 = a0 ? *(const bf16x8*)&Bls[nbase1 + 192] : zf;
            acc00 = __builtin_amdgcn_mfma_f32_16x16x32_bf16(xh0, bh0, acc00, 0, 0, 0);
            acc00 = __builtin_amdgcn_mfma_f32_16x16x32_bf16(xh0, bl0, acc00, 0, 0, 0);
            acc00 = __builtin_amdgcn_mfma_f32_16x16x32_bf16(xl0, bh0, acc00, 0, 0, 0);
            acc01 = __builtin_amdgcn_mfma_f32_16x16x32_bf16(xh0, bh1, acc01, 0, 0, 0);
            acc01 = __builtin_amdgcn_mfma_f32_16x16x32_bf16(xh0, bl1, acc01, 0, 0, 0);
            acc01 = __builtin_amdgcn_mfma_f32_16x16x32_bf16(xl0, bh1, acc01, 0, 0, 0);
            acc10 = __builtin_amdgcn_mfma_f32_16x16x32_bf16(xh1, bh0, acc10, 0, 0, 0);
            acc10 = __builtin_amdgcn_mfma_f32_16x16x32_bf16(xh1, bl0, acc10, 0, 0, 0);
            acc10 = __builtin_amdgcn_mfma_f32_16x16x32_bf16(xl1, bh0, acc10, 0, 0, 0);
            acc11 = __builtin_amdgcn_mfma_f32_16x16x32_bf16(xh1, bh1, acc11, 0, 0, 0);
            acc11 = __builtin_amdgcn_mfma_f32_16x16x32_bf16(xh1, bl1, acc11, 0, 0, 0);
            acc11 = __builtin_amdgcn_mfma_f32_16x16x32_bf16(xl1, bh1, acc11, 0, 0, 0);
            pa_h0 = na_h0; pa_l0 = na_l0; pa_h1 = na_h1; pa_l1 = na_l1;
        }
        // epilogue: per-wave LDS transpose -> coalesced dwordx4 stores (128B segments)
        {
#pragma unroll
            for (int r = 0; r < 4; r++) {
                Tw[wid][q * 4 + r][l15] = acc00[r];
                Tw[wid][q * 4 + r][16 + l15] = acc01[r];
            }
            float4 v0 = *(const float4*)&Tw[wid][tr][tc];
            float4 v1 = *(const float4*)&Tw[wid][8 + tr][tc];
            if (cval) {
                int rg0 = it * 128 + wm * 32 + tr;
                float4 o0, o1;
                o0.x = 1.f / (1.f + __expf(-(v0.x + bb.x)));
                o0.y = 1.f / (1.f + __expf(-(v0.y + bb.y)));
                o0.z = 1.f / (1.f + __expf(-(v0.z + bb.z)));
                o0.w = 1.f / (1.f + __expf(-(v0.w + bb.w)));
                o1.x = 1.f / (1.f + __expf(-(v1.x + bb.x)));
                o1.y = 1.f / (1.f + __expf(-(v1.y + bb.y)));
                o1.z = 1.f / (1.f + __expf(-(v1.z + bb.z)));
                o1.w = 1.f / (1.f + __expf(-(v1.w + bb.w)));
                *(float4*)&out[(long long)rg0 * NENT + ceg] = o0;
                *(float4*)&out[(long long)(rg0 + 8) * NENT + ceg] = o1;
            }
        }
        {
#pragma unroll
            for (int r = 0; r < 4; r++) {
                Tw[wid][q * 4 + r][l15] = acc10[r];
                Tw[wid][q * 4 + r][16 + l15] = acc11[r];
            }
            float4 v0 = *(const float4*)&Tw[wid][tr][tc];
            float4 v1 = *(const float4*)&Tw[wid][8 + tr][tc];
            if (cval) {
                int rg0 = it * 128 + wm * 32 + 16 + tr;
                float4 o0, o1;
                o0.x = 1.f / (1.f + __expf(-(v0.x + bb.x)));
                o0.y = 1.f / (1.f + __expf(-(v0.y + bb.y)));
                o0.z = 1.f / (1.f + __expf(-(v0.z + bb.z)));
                o0.w = 1.f / (1.f + __expf(-(v0.w + bb.w)));
                o1.x = 1.f / (1.f + __expf(-(v1.x + bb.x)));
                o1.y = 1.f / (1.f + __expf(-(v1.y + bb.y)));
                o1.z = 1.f / (1.f + __expf(-(v1.z + bb.z)));
                o1.w = 1.f / (1.f + __expf(-(v1.w + bb.w)));
                *(float4*)&out[(long long)rg0 * NENT + ceg] = o0;
                *(float4*)&out[(long long)(rg0 + 8) * NENT + ceg] = o1;
            }
        }
        ah0 += STEP; al0 += STEP; ah1 += STEP; al1 += STEP;
    }
}

// ================= host =================

extern "C" void kernel_launch(void* const* d_in, const int* in_sizes, int n_in,
                              void* d_out, int out_size, void* d_ws, size_t ws_size,
                              hipStream_t stream) {
    const int*   sub      = (const int*)d_in[0];
    const int*   rel      = (const int*)d_in[1];
    const int*   ei       = (const int*)d_in[3];
    const int*   et       = (const int*)d_in[4];
    const int*   perm     = (const int*)d_in[5];
    const float* emb      = (const float*)d_in[6];
    const float* init_rel = (const float*)d_in[7];
    const float* w_in     = (const float*)d_in[8];
    const float* w_out    = (const float*)d_in[9];
    const float* w_loop   = (const float*)d_in[10];
    const float* w_rel    = (const float*)d_in[11];
    const float* loop_rel = (const float*)d_in[12];
    const float* bn0_g    = (const float*)d_in[13];
    const float* bn0_b    = (const float*)d_in[14];
    const float* bn1_g    = (const float*)d_in[15];
    const float* bn1_b    = (const float*)d_in[16];
    const float* bn2_g    = (const float*)d_in[17];
    const float* bn2_b    = (const float*)d_in[18];
    const float* filt     = (const float*)d_in[19];
    const float* fc_w     = (const float*)d_in[20];
    const float* fc_b     = (const float*)d_in[21];
    const float* bias_ent = (const float*)d_in[22];

    float* ws  = (float*)d_ws;
    float* o   = (float*)d_out;

    float* agg     = ws + OFF_AGG;
    float* agg_out = agg + (long long)NENT * DD;
    int*   cnt     = (int*)(ws + OFF_CNT);
    int*   cursor  = (int*)(ws + OFF_CURSOR);
    int*   bsum    = (int*)(ws + OFF_BSUM);
    int*   elist   = (int*)(ws + OFF_ELIST);
    ushort* wth    = (ushort*)(ws + OFF_WT);
    ushort* wtl    = wth + 3 * DD * DD;
    float* acc0    = ws + OFF_ACC0;
    float* acc1    = ws + OFF_ACC1;
    float* dinv    = ws + OFF_DINV;
    float* rmat    = ws + OFF_RMAT;
    float* cheq    = ws + OFF_CHEQ;
    float* bn1s    = ws + OFF_BN1S;
    ushort* x2h    = (ushort*)(ws + OFF_X2H);
    ushort* x2l    = (ushort*)(ws + OFF_X2L);
    ushort* aeh    = (ushort*)agg_out;            // bf16 planes over dead agg_out
    ushort* ael    = aeh + (long long)NENT * DD;

    // d_out scratch. all_ent f32 lives in the conv region BEFORE k_conv runs
    // (lifetime: k_allent -> k_cvt/k_cheq); k_conv then overwrites it.
    float*  all_ent  = o + OD_CONV;
    float*  conv_out = o + OD_CONV;
    ushort* fwh      = (ushort*)(o + OD_FWH);
    ushort* fwl      = (ushort*)(o + OD_FWL);
    float*  part     = o + OD_PART;

    hipMemsetAsync(ws + ZSTART, 0, (size_t)(ZEND - ZSTART) * 4, stream);

    // ---- CSR build + gather aggregation ----
    k_hist<<<(ETOT + 255) / 256, 256, 0, stream>>>(ei, cnt);
    k_dinv<<<(NENT + 255) / 256, 256, 0, stream>>>(cnt, dinv);
    k_scan1<<<98, 256, 0, stream>>>(cnt, bsum);
    k_scan2<<<1, 128, 0, stream>>>(bsum);
    k_scan3<<<98, 256, 0, stream>>>(cnt, bsum, cursor);
    k_fill<<<(ETOT + 255) / 256, 256, 0, stream>>>(ei, cursor, elist);
    k_agg<<<NSEG / 4, 256, 0, stream>>>(ei, et, cnt, elist, emb, init_rel, dinv, agg);

    // ---- encoder GEMMs + weight conversions ----
    k_cvt3w<<<(3 * DD * DD + 255) / 256, 256, 0, stream>>>(w_in, w_out, w_loop, wth, wtl);
    k_allent_mfma<<<dim3((NENT + 63) / 64, 2), 256, 0, stream>>>(agg, emb, loop_rel,
                                                                 wth, wtl, all_ent);
    k_cvt<<<((NENT * DD / 4) + 255) / 256, 256, 0, stream>>>(all_ent, aeh, ael);
    k_cvtw<<<((DD * FLAT / 4) + 255) / 256, 256, 0, stream>>>(fc_w, fwh, fwl);
    k_rmat<<<400 / 16, 256, 0, stream>>>(init_rel, w_rel, rmat);

    // ---- decoder ----
    k_cheq<<<(BB * 400) / 256, 256, 0, stream>>>(sub, rel, perm, all_ent, rmat, cheq, acc0);
    k_conv<<<BB, 256, 0, stream>>>(cheq, acc0, bn0_g, bn0_b, filt, conv_out, acc1);
    k_bn1fin<<<1, 128, 0, stream>>>(acc1, bn1_g, bn1_b, bn1s);
    k_fc_mfma<<<dim3(BB / 64, FC_KS), 512, 0, stream>>>(conv_out, bn1s, fwh, fwl, part);
    k_bn2<<<DD, 256, 0, stream>>>(part, fc_b, bn2_g, bn2_b, x2h, x2l);
    k_logits_mfma<<<(NENT + LE - 1) / LE, 512, 0, stream>>>(
        x2h, x2l, aeh, ael, bias_ent, o);
}

// Round 18
// 809.670 us; speedup vs baseline: 1.0620x; 1.0620x over previous
//
#include <hip/hip_runtime.h>

// ---------------- problem constants ----------------
#define ETOT  500000
#define EHALF 250000
#define NENT  50000
#define NSEG  (2 * NENT)   // segments: half*NENT + dst
#define DD    200
#define BB    1024
#define NF    96
#define FLAT  38400   // 96*400

// fc split-K config
#define FC_KS     20
#define FC_KSLICE 1920    // 38400/20
#define FC_NCHUNK 60      // 1920/32

// logits config
#define LE 64             // entities per block (LDS strip)

// ---------------- workspace layout (float32 offsets) ----------------
#define OFF_AGG      0LL          // 20,000,000  ([0,10M)=agg_in, [10M,20M)=agg_out->aeh/ael)
// zeroed region: [ZSTART, ZEND)
#define ZSTART       20000000LL
#define OFF_CNT      20000000LL   // 100,004 ints (NSEG+1 used; becomes row_start after scan)
#define OFF_ACC0     20100004LL   //          2  (bn0 sum, sumsq)
#define OFF_ACC1     20100006LL   //        192  (bn1 sum[96], sumsq[96])
#define ZEND         20100198LL
// non-zeroed:
#define OFF_CURSOR   20304998LL   //    100,000 ints
#define OFF_BSUM     20404998LL   //        128 ints
#define OFF_ELIST    20405126LL   //    500,000 ints (dead after k_agg; wt planes reuse it)
#define OFF_WT       20405128LL   //    120,000 f32 = 240,000 ushort (3 transposed w hi+lo), 16B-aligned
#define OFF_DINV     20905126LL   //     50,000
#define OFF_RMAT     20955126LL   //     80,000
#define OFF_CHEQ     21035126LL   //    409,600
#define OFF_BN1S     21444726LL   //        192  (scale[96], shift[96])
#define OFF_X2H      21649720LL   //    102,400 f32 (= 204,800 ushort), 16B-aligned
#define OFF_X2L      21752120LL   //    102,400 f32
// total ws need ~= 21,854,520 f32 = 87.4 MB

// ---------------- d_out scratch layout (f32 offsets; out_size = 51,200,000) ----
// OD_CONV region is time-shared: [k_allent..k_cheq] it holds all_ent f32 (10M);
// from k_conv on it holds conv_out (39.3M). Strictly stream-ordered, no overlap in time.
#define OD_CONV 0LL          // 39,321,600 (1024 x 38400 conv output, f32)
#define OD_FWH  39321600LL   //  3,840,000 f32 = 7,680,000 ushort (fc_w hi plane)
#define OD_FWL  43161600LL   //  3,840,000 f32 (fc_w lo plane)
#define OD_PART 47001600LL   //  4,096,000 f32 (FC_KS x 1024 x 200 partials) -> ends 51,097,600

typedef __attribute__((ext_vector_type(8))) short bf16x8;
typedef __attribute__((ext_vector_type(4))) float f32x4;

__device__ inline void bf16split(float v, ushort& h, ushort& l) {
    unsigned u = __float_as_uint(v);
    unsigned hu = u & 0xffff0000u;
    h = (ushort)(hu >> 16);
    float lf = v - __uint_as_float(hu);
    l = (ushort)(__float_as_uint(lf) >> 16);
}

__device__ inline void split8(const float* e, bf16x8& h8, bf16x8& l8) {
#pragma unroll
    for (int t = 0; t < 8; t++) {
        ushort h, l;
        bf16split(e[t], h, l);
        h8[t] = (short)h;
        l8[t] = (short)l;
    }
}

// ================= CSR build =================

__global__ void k_hist(const int* __restrict__ ei, int* __restrict__ cnt) {
    int e = blockIdx.x * 256 + threadIdx.x;
    if (e < ETOT) {
        int seg = (e < EHALF ? 0 : NENT) + ei[ETOT + e];
        atomicAdd(&cnt[seg], 1);
    }
}

__global__ void k_dinv(const int* __restrict__ cnt, float* __restrict__ dinv) {
    int i = blockIdx.x * 256 + threadIdx.x;
    if (i < NENT) {
        int d = cnt[i] + cnt[NENT + i];
        dinv[i] = d > 0 ? rsqrtf((float)d) : 0.f;
    }
}

__global__ void k_scan1(int* __restrict__ cnt, int* __restrict__ bsum) {
    __shared__ int S[256];
    int base = blockIdx.x * 1024 + threadIdx.x * 4;
    int v[4], s = 0;
#pragma unroll
    for (int i = 0; i < 4; i++) { v[i] = (base + i <= NSEG) ? cnt[base + i] : 0; s += v[i]; }
    S[threadIdx.x] = s;
    __syncthreads();
    for (int off = 1; off < 256; off <<= 1) {
        int t = (threadIdx.x >= off) ? S[threadIdx.x - off] : 0;
        __syncthreads();
        S[threadIdx.x] += t;
        __syncthreads();
    }
    int run = S[threadIdx.x] - s;
#pragma unroll
    for (int i = 0; i < 4; i++) {
        if (base + i <= NSEG) cnt[base + i] = run;
        run += v[i];
    }
    if (threadIdx.x == 255) bsum[blockIdx.x] = S[255];
}

__global__ void k_scan2(int* __restrict__ bsum) {
    __shared__ int S[128];
    int v = (threadIdx.x < 98) ? bsum[threadIdx.x] : 0;
    S[threadIdx.x] = v;
    __syncthreads();
    for (int off = 1; off < 128; off <<= 1) {
        int t = (threadIdx.x >= off) ? S[threadIdx.x - off] : 0;
        __syncthreads();
        S[threadIdx.x] += t;
        __syncthreads();
    }
    if (threadIdx.x < 98) bsum[threadIdx.x] = S[threadIdx.x] - v;
}

__global__ void k_scan3(int* __restrict__ cnt, const int* __restrict__ bsum,
                        int* __restrict__ cursor) {
    int add = bsum[blockIdx.x];
    int base = blockIdx.x * 1024 + threadIdx.x * 4;
#pragma unroll
    for (int i = 0; i < 4; i++) {
        int idx = base + i;
        if (idx <= NSEG) {
            int v = cnt[idx] + add;
            cnt[idx] = v;
            if (idx < NSEG) cursor[idx] = v;
        }
    }
}

__global__ void k_fill(const int* __restrict__ ei, int* __restrict__ cursor,
                       int* __restrict__ elist) {
    int e = blockIdx.x * 256 + threadIdx.x;
    if (e < ETOT) {
        int seg = (e < EHALF ? 0 : NENT) + ei[ETOT + e];
        int pos = atomicAdd(&cursor[seg], 1);
        elist[pos] = e;
    }
}

// gather-aggregate: one wave per segment (4 waves/block), no float atomics.
// Index loads software-pipelined one edge ahead.
__global__ void k_agg(const int* __restrict__ ei, const int* __restrict__ et,
                      const int* __restrict__ row_start, const int* __restrict__ elist,
                      const float* __restrict__ emb, const float* __restrict__ rel,
                      const float* __restrict__ dinv, float* __restrict__ agg) {
    int seg = blockIdx.x * 4 + (threadIdx.x >> 6);
    int lane = threadIdx.x & 63;
    int dst = seg - (seg >= NENT ? NENT : 0);
    float dd = dinv[dst];
    int s = row_start[seg], e = row_start[seg + 1];
    bool act = lane < 50;
    float4 acc = {0.f, 0.f, 0.f, 0.f};
    if (s < e) {
        int ed = elist[s];
        int src = ei[ed];
        int t = et[ed];
        for (int i = s; i < e; i++) {
            int src_c = src, t_c = t;
            if (i + 1 < e) {
                int ed2 = elist[i + 1];
                src = ei[ed2];
                t = et[ed2];
            }
            float nrm = dinv[src_c] * dd;
            if (act) {
                float4 a = *(const float4*)&emb[(long long)src_c * DD + lane * 4];
                float4 b = *(const float4*)&rel[t_c * DD + lane * 4];
                acc.x += (a.x - b.x) * nrm;
                acc.y += (a.y - b.y) * nrm;
                acc.z += (a.z - b.z) * nrm;
                acc.w += (a.w - b.w) * nrm;
            }
        }
    }
    if (act) *(float4*)&agg[(long long)seg * DD + lane * 4] = acc;
}

// ================= encoder GEMMs =================

// transpose + hi/lo-split the three 200x200 weights: wt[s][j][k] = split(w_s[k][j])
__global__ void k_cvt3w(const float* __restrict__ w_in, const float* __restrict__ w_out,
                        const float* __restrict__ w_loop,
                        ushort* __restrict__ wth, ushort* __restrict__ wtl) {
    int idx = blockIdx.x * 256 + threadIdx.x;
    if (idx >= 3 * DD * DD) return;
    int s = idx / (DD * DD);
    int rem = idx - s * DD * DD;
    int j = rem / DD, k = rem - (rem / DD) * DD;
    const float* w = (s == 0) ? w_in : (s == 1) ? w_out : w_loop;
    ushort h, l;
    bf16split(w[k * DD + j], h, l);
    wth[idx] = h;
    wtl[idx] = l;
}

// all_ent = tanh((agg_in@w_in + agg_out@w_out + (emb-loop_rel)@w_loop)/3) via bf16-split MFMA.
__global__ __launch_bounds__(256) void k_allent_mfma(
        const float* __restrict__ agg, const float* __restrict__ emb,
        const float* __restrict__ loop_rel,
        const ushort* __restrict__ wth, const ushort* __restrict__ wtl,
        float* __restrict__ all_ent) {
    __shared__ __align__(16) ushort Bh[2][112][36];   // stride 36 -> 2-way banks (free)
    __shared__ __align__(16) ushort Bl[2][112][36];
    __shared__ float lr[DD];
    int tid = threadIdx.x;
    for (int i = tid; i < DD; i += 256) lr[i] = loop_rel[i];
    int wid = tid >> 6, lane = tid & 63, l15 = lane & 15, q = lane >> 4;
    int r0 = blockIdx.x * 64;
    int nh = blockIdx.y;
    int row = r0 + wid * 16 + l15;
    if (row > NENT - 1) row = NENT - 1;
    const float* apa = &agg[(long long)row * DD];
    const float* apb = &agg[(long long)(NENT + row) * DD];
    const float* apc = &emb[(long long)row * DD];

    bool stg = tid < 224;
    int srow = tid - (tid >= 112 ? 112 : 0);
    if (srow > 111) srow = 0;
    bool spl = (tid >= 112) && stg;
    int sj = nh * 112 + srow;
    int sjr = sj < DD ? sj : DD - 1;
    const ushort* bplane = spl ? wtl : wth;
    int srowoff = sjr * DD;
    ushort* d0 = spl ? &Bl[0][srow][0] : &Bh[0][srow][0];
    ushort* d1 = spl ? &Bl[1][srow][0] : &Bh[1][srow][0];

    f32x4 zero4 = {0.f, 0.f, 0.f, 0.f};
    f32x4 acc[7];
#pragma unroll
    for (int n = 0; n < 7; n++) acc[n] = zero4;

    uint4 w0 = {0u,0u,0u,0u}, w1 = {0u,0u,0u,0u}, w2 = {0u,0u,0u,0u}, w3 = {0u,0u,0u,0u};
    if (stg) {
        const ushort* src = bplane + srowoff;
        w0 = *(const uint4*)&src[0];
        w1 = *(const uint4*)&src[8];
        w2 = *(const uint4*)&src[16];
        w3 = *(const uint4*)&src[24];
        *(uint4*)&d0[0]  = w0;
        *(uint4*)&d0[8]  = w1;
        *(uint4*)&d0[16] = w2;
        *(uint4*)&d0[24] = w3;
    }
    float4 a1, a2;
    {
        int k0 = q * 8;
        a1 = *(const float4*)&apa[k0];
        a2 = *(const float4*)&apa[k0 + 4];
    }
    __syncthreads();

    for (int t = 0; t < 21; t++) {
        int buf = t & 1;
        int s = t / 7, kk = t - s * 7;
        bool prt = (kk == 6);
        int k0 = prt ? 192 : kk * 32 + q * 8;
        bool act = !prt || (q == 0);
        bool more = (t + 1 < 21);
        if (stg && more) {
            int t2 = t + 1, ss = t2 / 7, k2 = t2 - ss * 7;
            bool p2 = (k2 == 6);
            int koff2 = p2 ? 192 : k2 * 32;
            const ushort* src = bplane + ss * (DD * DD) + srowoff + koff2;
            uint4 zz = {0u,0u,0u,0u};
            w0 = *(const uint4*)&src[0];
            w1 = p2 ? zz : *(const uint4*)&src[8];
            w2 = p2 ? zz : *(const uint4*)&src[16];
            w3 = p2 ? zz : *(const uint4*)&src[24];
        }
        float4 n1 = {0.f, 0.f, 0.f, 0.f}, n2 = {0.f, 0.f, 0.f, 0.f};
        if (more) {
            int t2 = t + 1, ss = t2 / 7, k2 = t2 - ss * 7;
            bool p2 = (k2 == 6);
            int ka = p2 ? 192 : k2 * 32 + q * 8;
            const float* apn = (ss == 0) ? apa : (ss == 1) ? apb : apc;
            if (!p2 || q == 0) {
                n1 = *(const float4*)&apn[ka];
                n2 = *(const float4*)&apn[ka + 4];
            }
        }
        float e[8] = {0.f, 0.f, 0.f, 0.f, 0.f, 0.f, 0.f, 0.f};
        if (act) {
            float4 v1 = a1, v2 = a2;
            if (s == 2) {
                float4 u1 = *(const float4*)&lr[k0];
                float4 u2 = *(const float4*)&lr[k0 + 4];
                v1.x -= u1.x; v1.y -= u1.y; v1.z -= u1.z; v1.w -= u1.w;
                v2.x -= u2.x; v2.y -= u2.y; v2.z -= u2.z; v2.w -= u2.w;
            }
            e[0] = v1.x; e[1] = v1.y; e[2] = v1.z; e[3] = v1.w;
            e[4] = v2.x; e[5] = v2.y; e[6] = v2.z; e[7] = v2.w;
        }
        bf16x8 ah, al;
        split8(e, ah, al);
#pragma unroll
        for (int n = 0; n < 7; n++) {
            bf16x8 bh = *(const bf16x8*)&Bh[buf][n * 16 + l15][q * 8];
            bf16x8 bl = *(const bf16x8*)&Bl[buf][n * 16 + l15][q * 8];
            acc[n] = __builtin_amdgcn_mfma_f32_16x16x32_bf16(ah, bh, acc[n], 0, 0, 0);
            acc[n] = __builtin_amdgcn_mfma_f32_16x16x32_bf16(ah, bl, acc[n], 0, 0, 0);
            acc[n] = __builtin_amdgcn_mfma_f32_16x16x32_bf16(al, bh, acc[n], 0, 0, 0);
        }
        if (stg && more) {
            ushort* d = buf ? d0 : d1;
            *(uint4*)&d[0]  = w0;
            *(uint4*)&d[8]  = w1;
            *(uint4*)&d[16] = w2;
            *(uint4*)&d[24] = w3;
        }
        __syncthreads();
        a1 = n1; a2 = n2;
    }
#pragma unroll
    for (int n = 0; n < 7; n++) {
        int j = nh * 112 + n * 16 + l15;
        if (j < DD) {
            int rowb = r0 + wid * 16 + q * 4;
#pragma unroll
            for (int r = 0; r < 4; r++) {
                if (rowb + r < NENT)
                    all_ent[(long long)(rowb + r) * DD + j] = tanhf(acc[n][r] * (1.f / 3.f));
            }
        }
    }
}

// convert all_ent f32 -> bf16 hi/lo (over agg_out region), 4 elems/thread
__global__ void k_cvt(const float* __restrict__ src, ushort* __restrict__ hi,
                      ushort* __restrict__ lo) {
    long long i = (long long)(blockIdx.x * 256 + threadIdx.x) * 4;
    if (i >= (long long)NENT * DD) return;
    float4 v = *(const float4*)&src[i];
    ushort4 h, l;
    bf16split(v.x, h.x, l.x);
    bf16split(v.y, h.y, l.y);
    bf16split(v.z, h.z, l.z);
    bf16split(v.w, h.w, l.w);
    *(ushort4*)&hi[i] = h;
    *(ushort4*)&lo[i] = l;
}

// convert fc_w f32 -> bf16 hi/lo planes (into d_out tail)
__global__ void k_cvtw(const float* __restrict__ src, ushort* __restrict__ hi,
                       ushort* __restrict__ lo) {
    long long i = (long long)(blockIdx.x * 256 + threadIdx.x) * 4;
    if (i >= (long long)DD * FLAT) return;
    float4 v = *(const float4*)&src[i];
    ushort4 h, l;
    bf16split(v.x, h.x, l.x);
    bf16split(v.y, h.y, l.y);
    bf16split(v.z, h.z, l.z);
    bf16split(v.w, h.w, l.w);
    *(ushort4*)&hi[i] = h;
    *(ushort4*)&lo[i] = l;
}

__global__ void k_rmat(const float* __restrict__ init_rel, const float* __restrict__ w_rel,
                       float* __restrict__ rmat) {
    __shared__ float S[16][DD];
    int r0 = blockIdx.x * 16;
    for (int i = threadIdx.x; i < 16 * DD; i += 256)
        S[i / DD][i % DD] = init_rel[(r0 + i / DD) * DD + i % DD];
    __syncthreads();
    int j = threadIdx.x;
    if (j < DD) {
        float acc[16];
#pragma unroll
        for (int rr = 0; rr < 16; rr++) acc[rr] = 0.f;
        for (int k = 0; k < DD; k += 4) {
            float wx = w_rel[(k + 0) * DD + j], wy = w_rel[(k + 1) * DD + j],
                  wz = w_rel[(k + 2) * DD + j], ww = w_rel[(k + 3) * DD + j];
#pragma unroll
            for (int rr = 0; rr < 16; rr++) {
                float4 a = *(const float4*)&S[rr][k];
                acc[rr] += a.x * wx + a.y * wy + a.z * wz + a.w * ww;
            }
        }
#pragma unroll
        for (int rr = 0; rr < 16; rr++) rmat[(r0 + rr) * DD + j] = acc[rr];
    }
}

// ================= decoder =================

__global__ void k_cheq(const int* __restrict__ sub, const int* __restrict__ rel,
                       const int* __restrict__ perm, const float* __restrict__ all_ent,
                       const float* __restrict__ rmat, float* __restrict__ cheq,
                       float* __restrict__ acc0) {
    int i = blockIdx.x * 256 + threadIdx.x;
    int b = i / 400, p = i % 400;
    int c = perm[p];
    float v = (c < DD) ? all_ent[(long long)sub[b] * DD + c]
                       : rmat[rel[b] * DD + (c - DD)];
    cheq[i] = v;
    __shared__ float s1[256], s2[256];
    s1[threadIdx.x] = v;
    s2[threadIdx.x] = v * v;
    __syncthreads();
    for (int st = 128; st > 0; st >>= 1) {
        if (threadIdx.x < st) { s1[threadIdx.x] += s1[threadIdx.x + st]; s2[threadIdx.x] += s2[threadIdx.x + st]; }
        __syncthreads();
    }
    if (threadIdx.x == 0) { atomicAdd(&acc0[0], s1[0]); atomicAdd(&acc0[1], s2[0]); }
}

// bn0-normalize + circular pad + 9x9 conv + bn1 stats (register sliding window).
__global__ void k_conv(const float* __restrict__ cheq, const float* __restrict__ acc0,
                       const float* __restrict__ bn0_g, const float* __restrict__ bn0_b,
                       const float* __restrict__ filt, float* __restrict__ conv_out,
                       float* __restrict__ acc1) {
    __shared__ __align__(16) float xp[28][36];   // 4 KB
    __shared__ float fl[NF * 81];                // 31.1 KB
    __shared__ float csum[NF], csq[NF];
    int b = blockIdx.x;
    const float invN = 1.f / (BB * 400.f);
    float mean = acc0[0] * invN;
    float var = acc0[1] * invN - mean * mean;
    float sc = rsqrtf(var + 1e-5f) * bn0_g[0];
    float sh = bn0_b[0] - mean * sc;
    for (int i = threadIdx.x; i < 28 * 28; i += 256) {
        int r = i / 28, c = i % 28;
        int rr = (r + 16) % 20, cc = (c + 16) % 20;
        xp[r][c] = cheq[b * 400 + rr * 20 + cc] * sc + sh;
    }
    for (int i = threadIdx.x; i < NF * 81; i += 256) fl[i] = filt[i];
    if (threadIdx.x < NF) { csum[threadIdx.x] = 0.f; csq[threadIdx.x] = 0.f; }
    __syncthreads();
    for (int t = threadIdx.x; t < NF * 20; t += 256) {
        int ch = t / 20, row = t % 20;
        float acc[20];
#pragma unroll
        for (int c2 = 0; c2 < 20; c2++) acc[c2] = 0.f;
        for (int di = 0; di < 9; di++) {
            float xr[28];
#pragma unroll
            for (int g = 0; g < 7; g++) {
                float4 v = *(const float4*)&xp[row + di][g * 4];
                xr[g * 4 + 0] = v.x; xr[g * 4 + 1] = v.y;
                xr[g * 4 + 2] = v.z; xr[g * 4 + 3] = v.w;
            }
            float f[9];
#pragma unroll
            for (int dj = 0; dj < 9; dj++) f[dj] = fl[ch * 81 + di * 9 + dj];
#pragma unroll
            for (int dj = 0; dj < 9; dj++)
#pragma unroll
                for (int c2 = 0; c2 < 20; c2++)
                    acc[c2] = fmaf(xr[c2 + dj], f[dj], acc[c2]);
        }
        float s = 0.f, q = 0.f;
        long long base = (long long)b * FLAT + ch * 400 + row * 20;
#pragma unroll
        for (int c2 = 0; c2 < 20; c2++) {
            float v = acc[c2];
            s += v; q += v * v;
            conv_out[base + c2] = v;
        }
        atomicAdd(&csum[ch], s);
        atomicAdd(&csq[ch], q);
    }
    __syncthreads();
    if (threadIdx.x < NF) {
        atomicAdd(&acc1[threadIdx.x], csum[threadIdx.x]);
        atomicAdd(&acc1[NF + threadIdx.x], csq[threadIdx.x]);
    }
}

__global__ void k_bn1fin(const float* __restrict__ acc1, const float* __restrict__ g1,
                         const float* __restrict__ b1, float* __restrict__ bn1s) {
    int c = threadIdx.x;
    if (c >= NF) return;
    const float invN = 1.f / (BB * 400.f);
    float m = acc1[c] * invN;
    float v = acc1[NF + c] * invN - m * m;
    float sc = rsqrtf(v + 1e-5f) * g1[c];
    bn1s[c] = sc;
    bn1s[NF + c] = b1[c] - m * sc;
}

// ---- fc GEMM via bf16-split MFMA: LDS-staged B, spill-free (round 12 proven form) ----
__global__ __launch_bounds__(256) void k_fc_mfma(
        const float* __restrict__ conv_out, const float* __restrict__ bn1s,
        const ushort* __restrict__ fwh, const ushort* __restrict__ fwl,
        float* __restrict__ part) {
    __shared__ __align__(16) ushort Bh[2][112][36];
    __shared__ __align__(16) ushort Bl[2][112][36];
    __shared__ float bns[192];
    int tid = threadIdx.x;
    for (int i = tid; i < 192; i += 256) bns[i] = bn1s[i];
    int wid = tid >> 6, lane = tid & 63, l15 = lane & 15, q = lane >> 4;
    int b0 = blockIdx.x * 64;
    int nh = blockIdx.y;
    int ksl = blockIdx.z;
    int kbase = ksl * FC_KSLICE;

    const float* ap = conv_out + (long long)(b0 + wid * 16 + l15) * FLAT;

    bool stg = tid < 224;
    int srow = tid - (tid >= 112 ? 112 : 0);
    if (srow > 111) srow = 0;
    bool spl = (tid >= 112) && stg;
    int sj = nh * 112 + srow;
    int sjr = sj < DD ? sj : DD - 1;
    const ushort* bsrc = (spl ? fwl : fwh) + (long long)sjr * FLAT + kbase;
    ushort* d0 = spl ? &Bl[0][srow][0] : &Bh[0][srow][0];
    ushort* d1 = spl ? &Bl[1][srow][0] : &Bh[1][srow][0];

    f32x4 zero4 = {0.f, 0.f, 0.f, 0.f};
    f32x4 acc[7];
#pragma unroll
    for (int n = 0; n < 7; n++) acc[n] = zero4;

    uint4 s0 = {0u,0u,0u,0u}, s1 = {0u,0u,0u,0u}, s2 = {0u,0u,0u,0u}, s3 = {0u,0u,0u,0u};
    if (stg) {
        s0 = *(const uint4*)&bsrc[0];
        s1 = *(const uint4*)&bsrc[8];
        s2 = *(const uint4*)&bsrc[16];
        s3 = *(const uint4*)&bsrc[24];
        *(uint4*)&d0[0]  = s0;
        *(uint4*)&d0[8]  = s1;
        *(uint4*)&d0[16] = s2;
        *(uint4*)&d0[24] = s3;
    }
    float4 a1, a2;
    {
        int k0 = kbase + q * 8;
        a1 = *(const float4*)&ap[k0];
        a2 = *(const float4*)&ap[k0 + 4];
    }
    __syncthreads();

    for (int c = 0; c < FC_NCHUNK; c++) {
        int buf = c & 1;
        int kc = kbase + c * 32 + q * 8;
        bool more = (c + 1 < FC_NCHUNK);
        if (stg && more) {
            int kn = (c + 1) * 32;
            s0 = *(const uint4*)&bsrc[kn];
            s1 = *(const uint4*)&bsrc[kn + 8];
            s2 = *(const uint4*)&bsrc[kn + 16];
            s3 = *(const uint4*)&bsrc[kn + 24];
        }
        float4 n1 = {0.f, 0.f, 0.f, 0.f}, n2 = {0.f, 0.f, 0.f, 0.f};
        if (more) {
            n1 = *(const float4*)&ap[kc + 32];
            n2 = *(const float4*)&ap[kc + 36];
        }
        int ch = kc / 400;
        float sc = bns[ch], sh = bns[96 + ch];
        float e[8] = {
            fmaxf(a1.x * sc + sh, 0.f), fmaxf(a1.y * sc + sh, 0.f),
            fmaxf(a1.z * sc + sh, 0.f), fmaxf(a1.w * sc + sh, 0.f),
            fmaxf(a2.x * sc + sh, 0.f), fmaxf(a2.y * sc + sh, 0.f),
            fmaxf(a2.z * sc + sh, 0.f), fmaxf(a2.w * sc + sh, 0.f)};
        bf16x8 ah, al;
        split8(e, ah, al);
#pragma unroll
        for (int n = 0; n < 7; n++) {
            bf16x8 bh = *(const bf16x8*)&Bh[buf][n * 16 + l15][q * 8];
            bf16x8 bl = *(const bf16x8*)&Bl[buf][n * 16 + l15][q * 8];
            acc[n] = __builtin_amdgcn_mfma_f32_16x16x32_bf16(ah, bh, acc[n], 0, 0, 0);
            acc[n] = __builtin_amdgcn_mfma_f32_16x16x32_bf16(ah, bl, acc[n], 0, 0, 0);
            acc[n] = __builtin_amdgcn_mfma_f32_16x16x32_bf16(al, bh, acc[n], 0, 0, 0);
        }
        if (stg && more) {
            ushort* d = buf ? d0 : d1;
            *(uint4*)&d[0]  = s0;
            *(uint4*)&d[8]  = s1;
            *(uint4*)&d[16] = s2;
            *(uint4*)&d[24] = s3;
        }
        __syncthreads();
        a1 = n1; a2 = n2;
    }
    long long pbase = (long long)ksl * (BB * DD);
#pragma unroll
    for (int n = 0; n < 7; n++) {
        int j = nh * 112 + n * 16 + l15;
        if (j < DD) {
            int rowb = b0 + wid * 16 + q * 4;
#pragma unroll
            for (int r = 0; r < 4; r++)
                part[pbase + (long long)(rowb + r) * DD + j] = acc[n][r];
        }
    }
}

// bn2 over batch, folding the split-K reduction; emits x2 bf16 hi/lo only
__global__ void k_bn2(const float* __restrict__ part, const float* __restrict__ fc_b,
                      const float* __restrict__ g2, const float* __restrict__ b2,
                      ushort* __restrict__ x2h, ushort* __restrict__ x2l) {
    int j = blockIdx.x;
    float vals[4];
    float s = 0.f, q = 0.f;
#pragma unroll
    for (int i = 0; i < 4; i++) {
        int b = threadIdx.x + i * 256;
        float v = fc_b[j];
#pragma unroll
        for (int ks = 0; ks < FC_KS; ks++)
            v += part[(long long)ks * (BB * DD) + (long long)b * DD + j];
        vals[i] = v;
        s += v; q += v * v;
    }
    __shared__ float r1[256], r2[256];
    __shared__ float bc[2];
    r1[threadIdx.x] = s; r2[threadIdx.x] = q;
    __syncthreads();
    for (int st = 128; st > 0; st >>= 1) {
        if (threadIdx.x < st) { r1[threadIdx.x] += r1[threadIdx.x + st]; r2[threadIdx.x] += r2[threadIdx.x + st]; }
        __syncthreads();
    }
    if (threadIdx.x == 0) {
        float m = r1[0] * (1.f / BB);
        float v = r2[0] * (1.f / BB) - m * m;
        float sc = rsqrtf(v + 1e-5f) * g2[j];
        bc[0] = sc; bc[1] = b2[j] - m * sc;
    }
    __syncthreads();
    float sc = bc[0], sh = bc[1];
#pragma unroll
    for (int i = 0; i < 4; i++) {
        int b = threadIdx.x + i * 256;
        float v = fmaxf(vals[i] * sc + sh, 0.f);
        ushort h, l;
        bf16split(v, h, l);
        x2h[b * DD + j] = h;
        x2l[b * DD + j] = l;
    }
}

// logits = sigmoid(x2 @ all_ent^T + bias) via bf16-split MFMA, B-strip-resident.
// (latency-floor kernel — unchanged)
__global__ __launch_bounds__(512) void k_logits_mfma(
        const ushort* __restrict__ x2h, const ushort* __restrict__ x2l,
        const ushort* __restrict__ aeh, const ushort* __restrict__ ael,
        const float* __restrict__ bias, float* __restrict__ out) {
    __shared__ ushort Bhs[LE * DD];            // 25.6 KB
    __shared__ ushort Bls[LE * DD];            // 25.6 KB
    __shared__ __align__(16) float Tw[8][16][36];   // 18.4 KB per-wave transpose tiles
    int e0 = blockIdx.x * LE;
    for (int i = threadIdx.x; i < 2 * LE * 25; i += 512) {   // 3200 uint4
        int pl = i >= LE * 25;
        int ii = pl ? i - LE * 25 : i;
        int row = ii / 25, seg = ii % 25;
        int e = e0 + row;
        if (e > NENT - 1) e = NENT - 1;
        const ushort* src = (pl ? ael : aeh) + (long long)e * DD + seg * 8;
        uint4 v = *(const uint4*)src;
        if (pl) *(uint4*)&Bls[row * DD + seg * 8] = v;
        else    *(uint4*)&Bhs[row * DD + seg * 8] = v;
    }
    __syncthreads();

    int wid = threadIdx.x >> 6;
    int lane = threadIdx.x & 63;
    int l15 = lane & 15, q = lane >> 4;
    int wm = wid >> 1;
    int wn = wid & 1;

    int nbase0 = (wn * 32 + l15) * DD;
    int nbase1 = (wn * 32 + 16 + l15) * DD;

    int tr = lane >> 3;            // 0..7 (+8 for second read)
    int tc = (lane & 7) * 4;       // 0..28
    int ceg = e0 + wn * 32 + tc;   // global entity col (4-aligned; NENT%4==0)
    bool cval = ceg < NENT;
    float4 bb = {0.f, 0.f, 0.f, 0.f};
    if (cval) bb = *(const float4*)&bias[ceg];

    f32x4 zero4 = {0.f, 0.f, 0.f, 0.f};
    bf16x8 zf = {0, 0, 0, 0, 0, 0, 0, 0};
    const int STEP = 128 * DD;

    const ushort* ah0 = x2h + (long long)(wm * 32 + l15) * DD;
    const ushort* al0 = x2l + (long long)(wm * 32 + l15) * DD;
    const ushort* ah1 = ah0 + 16 * DD;
    const ushort* al1 = al0 + 16 * DD;

    bf16x8 pa_h0, pa_l0, pa_h1, pa_l1;
    {
        int k0 = q * 8;
        pa_h0 = *(const bf16x8*)&ah0[k0];
        pa_l0 = *(const bf16x8*)&al0[k0];
        pa_h1 = *(const bf16x8*)&ah1[k0];
        pa_l1 = *(const bf16x8*)&al1[k0];
    }

    for (int it = 0; it < 8; it++) {
        f32x4 acc00 = zero4, acc01 = zero4, acc10 = zero4, acc11 = zero4;
#pragma unroll
        for (int kk = 0; kk < 6; kk++) {
            int kn = (kk < 5) ? (kk + 1) * 32 + q * 8 : 192;
            bf16x8 na_h0 = *(const bf16x8*)&ah0[kn];
            bf16x8 na_l0 = *(const bf16x8*)&al0[kn];
            bf16x8 na_h1 = *(const bf16x8*)&ah1[kn];
            bf16x8 na_l1 = *(const bf16x8*)&al1[kn];
            int kb = kk * 32 + q * 8;
            bf16x8 bh0 = *(const bf16x8*)&Bhs[nbase0 + kb];
            bf16x8 bl0 = *(const bf16x8*)&Bls[nbase0 + kb];
            bf16x8 bh1 = *(const bf16x8*)&Bhs[nbase1 + kb];
            bf16x8 bl1 = *(const bf16x8*)&Bls[nbase1 + kb];
            acc00 = __builtin_amdgcn_mfma_f32_16x16x32_bf16(pa_h0, bh0, acc00, 0, 0, 0);
            acc00 = __builtin_amdgcn_mfma_f32_16x16x32_bf16(pa_h0, bl0, acc00, 0, 0, 0);
            acc00 = __builtin_amdgcn_mfma_f32_16x16x32_bf16(pa_l0, bh0, acc00, 0, 0, 0);
            acc01 = __builtin_amdgcn_mfma_f32_16x16x32_bf16(pa_h0, bh1, acc01, 0, 0, 0);
            acc01 = __builtin_amdgcn_mfma_f32_16x16x32_bf16(pa_h0, bl1, acc01, 0, 0, 0);
            acc01 = __builtin_amdgcn_mfma_f32_16x16x32_bf16(pa_l0, bh1, acc01, 0, 0, 0);
            acc10 = __builtin_amdgcn_mfma_f32_16x16x32_bf16(pa_h1, bh0, acc10, 0, 0, 0);
            acc10 = __builtin_amdgcn_mfma_f32_16x16x32_bf16(pa_h1, bl0, acc10, 0, 0, 0);
            acc10 = __builtin_amdgcn_mfma_f32_16x16x32_bf16(pa_l1, bh0, acc10, 0, 0, 0);
            acc11 = __builtin_amdgcn_mfma_f32_16x16x32_bf16(pa_h1, bh1, acc11, 0, 0, 0);
            acc11 = __builtin_amdgcn_mfma_f32_16x16x32_bf16(pa_h1, bl1, acc11, 0, 0, 0);
            acc11 = __builtin_amdgcn_mfma_f32_16x16x32_bf16(pa_l1, bh1, acc11, 0, 0, 0);
            pa_h0 = na_h0; pa_l0 = na_l0; pa_h1 = na_h1; pa_l1 = na_l1;
        }
        {
            bf16x8 na_h0 = zf, na_l0 = zf, na_h1 = zf, na_l1 = zf;
            if (it + 1 < 8) {
                int k0 = q * 8;
                na_h0 = *(const bf16x8*)&ah0[STEP + k0];
                na_l0 = *(const bf16x8*)&al0[STEP + k0];
                na_h1 = *(const bf16x8*)&ah1[STEP + k0];
                na_l1 = *(const bf16x8*)&al1[STEP + k0];
            }
            bool a0 = (q == 0);
            bf16x8 xh0 = a0 ? pa_h0 : zf, xl0 = a0 ? pa_l0 : zf;
            bf16x8 xh1 = a0 ? pa_h1 : zf, xl1 = a0 ? pa_l1 : zf;
            bf16x8 bh0 = a0 ? *(const bf16x8*)&Bhs[nbase0 + 192] : zf;
            bf16x8 bl0 = a0 ? *(const bf16x8*)&Bls[nbase0 + 192] : zf;
            bf16x8 bh1 = a0 ? *(const bf16x8*)&Bhs[nbase1 + 192] : zf;
            bf16x8 bl1 = a0 ? *(const bf16x8*)&Bls[nbase1 + 192] : zf;
            acc00 = __builtin_amdgcn_mfma_f32_16x16x32_bf16(xh0, bh0, acc00, 0, 0, 0);
            acc00 = __builtin_amdgcn_mfma_f32_16x16x32_bf16(xh0, bl0, acc00, 0, 0, 0);
            acc00 = __builtin_amdgcn_mfma_f32_16x16x32_bf16(xl0, bh0, acc00, 0, 0, 0);
            acc01 = __builtin_amdgcn_mfma_f32_16x16x32_bf16(xh0, bh1, acc01, 0, 0, 0);
            acc01 = __builtin_amdgcn_mfma_f32_16x16x32_bf16(xh0, bl1, acc01, 0, 0, 0);
            acc01 = __builtin_amdgcn_mfma_f32_16x16x32_bf16(xl0, bh1, acc01, 0, 0, 0);
            acc10 = __builtin_amdgcn_mfma_f32_16x16x32_bf16(xh1, bh0, acc10, 0, 0, 0);
            acc10 = __builtin_amdgcn_mfma_f32_16x16x32_bf16(xh1, bl0, acc10, 0, 0, 0);
            acc10 = __builtin_amdgcn_mfma_f32_16x16x32_bf16(xl1, bh0, acc10, 0, 0, 0);
            acc11 = __builtin_amdgcn_mfma_f32_16x16x32_bf16(xh1, bh1, acc11, 0, 0, 0);
            acc11 = __builtin_amdgcn_mfma_f32_16x16x32_bf16(xh1, bl1, acc11, 0, 0, 0);
            acc11 = __builtin_amdgcn_mfma_f32_16x16x32_bf16(xl1, bh1, acc11, 0, 0, 0);
            pa_h0 = na_h0; pa_l0 = na_l0; pa_h1 = na_h1; pa_l1 = na_l1;
        }
        // epilogue: per-wave LDS transpose -> coalesced dwordx4 stores (128B segments)
        {
#pragma unroll
            for (int r = 0; r < 4; r++) {
                Tw[wid][q * 4 + r][l15] = acc00[r];
                Tw[wid][q * 4 + r][16 + l15] = acc01[r];
            }
            float4 v0 = *(const float4*)&Tw[wid][tr][tc];
            float4 v1 = *(const float4*)&Tw[wid][8 + tr][tc];
            if (cval) {
                int rg0 = it * 128 + wm * 32 + tr;
                float4 o0, o1;
                o0.x = 1.f / (1.f + __expf(-(v0.x + bb.x)));
                o0.y = 1.f / (1.f + __expf(-(v0.y + bb.y)));
                o0.z = 1.f / (1.f + __expf(-(v0.z + bb.z)));
                o0.w = 1.f / (1.f + __expf(-(v0.w + bb.w)));
                o1.x = 1.f / (1.f + __expf(-(v1.x + bb.x)));
                o1.y = 1.f / (1.f + __expf(-(v1.y + bb.y)));
                o1.z = 1.f / (1.f + __expf(-(v1.z + bb.z)));
                o1.w = 1.f / (1.f + __expf(-(v1.w + bb.w)));
                *(float4*)&out[(long long)rg0 * NENT + ceg] = o0;
                *(float4*)&out[(long long)(rg0 + 8) * NENT + ceg] = o1;
            }
        }
        {
#pragma unroll
            for (int r = 0; r < 4; r++) {
                Tw[wid][q * 4 + r][l15] = acc10[r];
                Tw[wid][q * 4 + r][16 + l15] = acc11[r];
            }
            float4 v0 = *(const float4*)&Tw[wid][tr][tc];
            float4 v1 = *(const float4*)&Tw[wid][8 + tr][tc];
            if (cval) {
                int rg0 = it * 128 + wm * 32 + 16 + tr;
                float4 o0, o1;
                o0.x = 1.f / (1.f + __expf(-(v0.x + bb.x)));
                o0.y = 1.f / (1.f + __expf(-(v0.y + bb.y)));
                o0.z = 1.f / (1.f + __expf(-(v0.z + bb.z)));
                o0.w = 1.f / (1.f + __expf(-(v0.w + bb.w)));
                o1.x = 1.f / (1.f + __expf(-(v1.x + bb.x)));
                o1.y = 1.f / (1.f + __expf(-(v1.y + bb.y)));
                o1.z = 1.f / (1.f + __expf(-(v1.z + bb.z)));
                o1.w = 1.f / (1.f + __expf(-(v1.w + bb.w)));
                *(float4*)&out[(long long)rg0 * NENT + ceg] = o0;
                *(float4*)&out[(long long)(rg0 + 8) * NENT + ceg] = o1;
            }
        }
        ah0 += STEP; al0 += STEP; ah1 += STEP; al1 += STEP;
    }
}

// ================= host =================

extern "C" void kernel_launch(void* const* d_in, const int* in_sizes, int n_in,
                              void* d_out, int out_size, void* d_ws, size_t ws_size,
                              hipStream_t stream) {
    const int*   sub      = (const int*)d_in[0];
    const int*   rel      = (const int*)d_in[1];
    const int*   ei       = (const int*)d_in[3];
    const int*   et       = (const int*)d_in[4];
    const int*   perm     = (const int*)d_in[5];
    const float* emb      = (const float*)d_in[6];
    const float* init_rel = (const float*)d_in[7];
    const float* w_in     = (const float*)d_in[8];
    const float* w_out    = (const float*)d_in[9];
    const float* w_loop   = (const float*)d_in[10];
    const float* w_rel    = (const float*)d_in[11];
    const float* loop_rel = (const float*)d_in[12];
    const float* bn0_g    = (const float*)d_in[13];
    const float* bn0_b    = (const float*)d_in[14];
    const float* bn1_g    = (const float*)d_in[15];
    const float* bn1_b    = (const float*)d_in[16];
    const float* bn2_g    = (const float*)d_in[17];
    const float* bn2_b    = (const float*)d_in[18];
    const float* filt     = (const float*)d_in[19];
    const float* fc_w     = (const float*)d_in[20];
    const float* fc_b     = (const float*)d_in[21];
    const float* bias_ent = (const float*)d_in[22];

    float* ws  = (float*)d_ws;
    float* o   = (float*)d_out;

    float* agg     = ws + OFF_AGG;
    float* agg_out = agg + (long long)NENT * DD;
    int*   cnt     = (int*)(ws + OFF_CNT);
    int*   cursor  = (int*)(ws + OFF_CURSOR);
    int*   bsum    = (int*)(ws + OFF_BSUM);
    int*   elist   = (int*)(ws + OFF_ELIST);
    ushort* wth    = (ushort*)(ws + OFF_WT);
    ushort* wtl    = wth + 3 * DD * DD;
    float* acc0    = ws + OFF_ACC0;
    float* acc1    = ws + OFF_ACC1;
    float* dinv    = ws + OFF_DINV;
    float* rmat    = ws + OFF_RMAT;
    float* cheq    = ws + OFF_CHEQ;
    float* bn1s    = ws + OFF_BN1S;
    ushort* x2h    = (ushort*)(ws + OFF_X2H);
    ushort* x2l    = (ushort*)(ws + OFF_X2L);
    ushort* aeh    = (ushort*)agg_out;            // bf16 planes over dead agg_out
    ushort* ael    = aeh + (long long)NENT * DD;

    // d_out scratch. all_ent f32 lives in the conv region BEFORE k_conv runs
    // (lifetime: k_allent -> k_cvt/k_cheq); k_conv then overwrites it.
    float*  all_ent  = o + OD_CONV;
    float*  conv_out = o + OD_CONV;
    ushort* fwh      = (ushort*)(o + OD_FWH);
    ushort* fwl      = (ushort*)(o + OD_FWL);
    float*  part     = o + OD_PART;

    hipMemsetAsync(ws + ZSTART, 0, (size_t)(ZEND - ZSTART) * 4, stream);

    // ---- CSR build + gather aggregation ----
    k_hist<<<(ETOT + 255) / 256, 256, 0, stream>>>(ei, cnt);
    k_dinv<<<(NENT + 255) / 256, 256, 0, stream>>>(cnt, dinv);
    k_scan1<<<98, 256, 0, stream>>>(cnt, bsum);
    k_scan2<<<1, 128, 0, stream>>>(bsum);
    k_scan3<<<98, 256, 0, stream>>>(cnt, bsum, cursor);
    k_fill<<<(ETOT + 255) / 256, 256, 0, stream>>>(ei, cursor, elist);
    k_agg<<<NSEG / 4, 256, 0, stream>>>(ei, et, cnt, elist, emb, init_rel, dinv, agg);

    // ---- encoder GEMMs + weight conversions ----
    k_cvt3w<<<(3 * DD * DD + 255) / 256, 256, 0, stream>>>(w_in, w_out, w_loop, wth, wtl);
    k_allent_mfma<<<dim3((NENT + 63) / 64, 2), 256, 0, stream>>>(agg, emb, loop_rel,
                                                                 wth, wtl, all_ent);
    k_cvt<<<((NENT * DD / 4) + 255) / 256, 256, 0, stream>>>(all_ent, aeh, ael);
    k_cvtw<<<((DD * FLAT / 4) + 255) / 256, 256, 0, stream>>>(fc_w, fwh, fwl);
    k_rmat<<<400 / 16, 256, 0, stream>>>(init_rel, w_rel, rmat);

    // ---- decoder ----
    k_cheq<<<(BB * 400) / 256, 256, 0, stream>>>(sub, rel, perm, all_ent, rmat, cheq, acc0);
    k_conv<<<BB, 256, 0, stream>>>(cheq, acc0, bn0_g, bn0_b, filt, conv_out, acc1);
    k_bn1fin<<<1, 128, 0, stream>>>(acc1, bn1_g, bn1_b, bn1s);
    k_fc_mfma<<<dim3(BB / 64, 2, FC_KS), 256, 0, stream>>>(conv_out, bn1s, fwh, fwl, part);
    k_bn2<<<DD, 256, 0, stream>>>(part, fc_b, bn2_g, bn2_b, x2h, x2l);
    k_logits_mfma<<<(NENT + LE - 1) / LE, 512, 0, stream>>>(
        x2h, x2l, aeh, ael, bias_ent, o);
}